// Round 8
// baseline (255.519 us; speedup 1.0000x reference)
//
#include <hip/hip_runtime.h>
#include <hip/hip_bf16.h>
#include <stdint.h>

#define NE    64
#define DIN   512
#define DOUT  512
#define TTOK  131072
#define BM    128
#define BN    128
#define BK    32
#define NK    (DIN / BK)              // 16 K-steps
#define TILES_TOTAL (TTOK / BM + NE)  // 1088
#define NXCD  8
#define TPX   (TILES_TOTAL / NXCD)    // 136

typedef __bf16 bf16x8_t __attribute__((ext_vector_type(8)));
typedef float  f32x4_t  __attribute__((ext_vector_type(4)));

// LDS (72 KB total -> 2 blocks/CU), ring-of-3 for counted-vmcnt pipelining:
//   A ring: 3 x 16384  (128 rows x 128B fp32 = 32 k; source-preswizzled (row&7))
//   B ring: 3 x 8192   (64 LDS rows x 128B bf16; row lr holds dout rows lr and
//                       lr+64, 32 k each; same (lr&7) XOR swizzle)
#define ABUF(i) ((i) * 16384)
#define BBUF(i) (49152 + (i) * 8192)
#define LDS_BYTES 73728

#define WAITV0() asm volatile("s_waitcnt vmcnt(0)" ::: "memory")
#define WAITV6() asm volatile("s_waitcnt vmcnt(6)" ::: "memory")
#define SB() __builtin_amdgcn_sched_barrier(0)

// ws layout: ws[0] = ntiles; tile table (int4) at ws+4; bf16 weight at +32KB
#define WBF_OFF 32768

__global__ void setup_tiles(const int* __restrict__ cnt, int* __restrict__ ws) {
    int e = threadIdx.x;
    if (e >= NE) return;
    int off = 0, tbase = 0;
    for (int i = 0; i < e; ++i) {
        int c = cnt[i];
        off += c;
        tbase += (c + (BM - 1)) / BM;
    }
    int c = cnt[e];
    int nt = (c + (BM - 1)) / BM;
    int* tbl = ws + 4;
    for (int t = 0; t < nt; ++t) {
        int idx = tbase + t;
        tbl[4 * idx + 0] = e;
        tbl[4 * idx + 1] = off + t * BM;
        tbl[4 * idx + 2] = off + c;
        tbl[4 * idx + 3] = 0;
    }
    if (e == NE - 1) ws[0] = tbase + nt;
}

// weight fp32 -> bf16, streaming (16.78M elems, 8 per thread-iter)
__global__ __launch_bounds__(256) void wcvt(const float* __restrict__ w,
                                            __bf16* __restrict__ wbf) {
    const size_t stride = (size_t)gridDim.x * 256;
    size_t i = (size_t)blockIdx.x * 256 + threadIdx.x;
    const size_t n8 = (size_t)NE * DOUT * DIN / 8;
    for (; i < n8; i += stride) {
        f32x4_t a = *(const f32x4_t*)(w + i * 8);
        f32x4_t b = *(const f32x4_t*)(w + i * 8 + 4);
        bf16x8_t h;
#pragma unroll
        for (int j = 0; j < 4; ++j) {
            h[j]     = (__bf16)a[j];
            h[4 + j] = (__bf16)b[j];
        }
        *(bf16x8_t*)(wbf + i * 8) = h;
    }
}

__device__ __forceinline__ void gload16(const void* g, uint8_t* l) {
    __builtin_amdgcn_global_load_lds(
        (const __attribute__((address_space(1))) uint32_t*)g,
        (__attribute__((address_space(3))) uint32_t*)l, 16, 0, 0);
}

__global__ __launch_bounds__(256, 2) void moe_gemm(
    const float* __restrict__ inp,
    const __bf16* __restrict__ wbf,
    const float* __restrict__ bias,
    const int* __restrict__ ws,
    float* __restrict__ out)
{
    __shared__ __align__(16) uint8_t smem[LDS_BYTES];

    const int bid  = blockIdx.x;
    const int xcd  = bid & (NXCD - 1);
    const int slot = bid >> 3;
    const int tile = xcd * TPX + (slot >> 2);
    const int n0   = (slot & 3) * BN;

    const int ntiles = ws[0];
    if (tile >= ntiles) return;
    const int4 ti = ((const int4*)(ws + 4))[tile];
    const int e = ti.x, row0 = ti.y, row_end = ti.z;

    const int tid  = threadIdx.x;
    const int lane = tid & 63;
    const int wave = tid >> 6;
    const int dr = lane >> 3;          // row-in-8-group
    const int ac = lane & 7;           // dest 16B chunk (linear)
    const int u  = ac ^ dr;            // logical chunk (group base % 8 == 0)

    // ---- A staging: 4 gload16/wave, each 8 rows x 128B, source-preswizzled ----
    const float* asrc[4];
#pragma unroll
    for (int i = 0; i < 4; ++i) {
        int arow = wave * 32 + i * 8 + dr;
        int grow = row0 + arow;
        if (grow > row_end - 1) grow = row_end - 1;   // clamp (C-stores guarded)
        asrc[i] = inp + (size_t)grow * DIN + (u << 2);
    }
    auto issueA = [&](int t, int buf) {
        uint8_t* dst = smem + ABUF(buf) + wave * 4096;
#pragma unroll
        for (int i = 0; i < 4; ++i)
            gload16(asrc[i] + t * BK, dst + i * 1024);
    };

    // ---- B staging: 2 gload16/wave. LDS row lr (0..63) chunk-logical u:
    //   u<4 -> dout n0+lr,   k-part u&3 ; u>=4 -> dout n0+lr+64, k-part u&3 ----
    const __bf16* bsrc[2];
#pragma unroll
    for (int i = 0; i < 2; ++i) {
        int lr = wave * 16 + i * 8 + dr;
        int dout = n0 + lr + ((u >> 2) << 6);
        bsrc[i] = wbf + (size_t)(e * DOUT + dout) * DIN + (u & 3) * 8;
    }
    auto issueB = [&](int t, int buf) {
        uint8_t* dst = smem + BBUF(buf) + wave * 2048;
#pragma unroll
        for (int i = 0; i < 2; ++i)
            gload16(bsrc[i] + t * BK, dst + i * 1024);
    };

    // ---- compute ----
    const int wr = (wave >> 1) * 64;
    const int wc = (wave & 1) * 64;
    const int frow = lane & 15;
    const int kg   = lane >> 4;        // 0..3: which 8-k group of the 32-k step

    f32x4_t acc[4][4] = {};

    auto compute = [&](int buf) {
        bf16x8_t af[4], bg[4];
#pragma unroll
        for (int m = 0; m < 4; ++m) {
            const int row = wr + m * 16 + frow;
            const uint8_t* pa = smem + ABUF(buf) + row * 128;
            const int sw = (row & 7) << 4;
            f32x4_t q0 = *(const f32x4_t*)(pa + ((kg * 32)      ^ sw));
            f32x4_t q1 = *(const f32x4_t*)(pa + ((kg * 32 + 16) ^ sw));
#pragma unroll
            for (int j = 0; j < 4; ++j) {
                af[m][j]     = (__bf16)q0[j];
                af[m][4 + j] = (__bf16)q1[j];
            }
        }
#pragma unroll
        for (int n = 0; n < 4; ++n) {
            const int row = wc + n * 16 + frow;     // dout-row in tile (0..127)
            const int lr  = row & 63;
            const int h   = row >> 6;
            bg[n] = *(const bf16x8_t*)(smem + BBUF(buf) + lr * 128 +
                                       ((h * 64 + kg * 16) ^ ((lr & 7) << 4)));
        }
        __builtin_amdgcn_s_setprio(1);
#pragma unroll
        for (int m = 0; m < 4; ++m)
#pragma unroll
            for (int n = 0; n < 4; ++n)
                acc[m][n] = __builtin_amdgcn_mfma_f32_16x16x32_bf16(
                    af[m], bg[n], acc[m][n], 0, 0, 0);
        __builtin_amdgcn_s_setprio(0);
    };

    // ---- counted-vmcnt ring-3 pipeline (T3+T4):
    // step t: issue set(t+2) -> compute(t) -> vmcnt(6) [certifies set(t+1),
    // leaves set(t+2)'s 6 loads in flight] -> barrier.
    // Set(t+1) flight = ~1.7 steps ~= 1000cy >= HBM latency.
    // Slot safety: set(t+2)'s DMA is issued after the barrier ending all
    // reads of that slot's previous tenant (set t-1) -> full-step margin. ----
    issueA(0, 0); issueB(0, 0);
    issueA(1, 1); issueB(1, 1);
    WAITV6(); SB();                    // set(0) done; set(1) flies on
    __builtin_amdgcn_s_barrier();
#pragma unroll
    for (int t = 0; t < NK; ++t) {
        if (t + 2 < NK) {
            issueA(t + 2, (t + 2) % 3);
            issueB(t + 2, (t + 2) % 3);
        }
        compute(t % 3);
        if (t + 1 < NK) {
            if (t + 2 < NK) { WAITV6(); } else { WAITV0(); }
            SB();
            __builtin_amdgcn_s_barrier();
        }
    }

    // ---- epilogue: C/D layout col = lane&15, row = (lane>>4)*4 + j [m89] ----
    const int crow = kg * 4;
    const int ccol = frow;
    float bv[4];
#pragma unroll
    for (int n = 0; n < 4; ++n)
        bv[n] = bias[e * DOUT + n0 + wc + n * 16 + ccol];
#pragma unroll
    for (int m = 0; m < 4; ++m) {
#pragma unroll
        for (int j = 0; j < 4; ++j) {
            const int grow = row0 + wr + m * 16 + crow + j;
            if (grow < row_end) {
                float* orow = out + (size_t)grow * DOUT + n0 + wc + ccol;
#pragma unroll
                for (int n = 0; n < 4; ++n)
                    orow[n * 16] = acc[m][n][j] + bv[n];
            }
        }
    }
}

extern "C" void kernel_launch(void* const* d_in, const int* in_sizes, int n_in,
                              void* d_out, int out_size, void* d_ws, size_t ws_size,
                              hipStream_t stream) {
    const float* inp    = (const float*)d_in[0];
    const float* weight = (const float*)d_in[1];
    const float* bias   = (const float*)d_in[2];
    const int* cnt      = (const int*)d_in[3];   // int64 in reference, delivered as int32
    float* out = (float*)d_out;
    int* ws = (int*)d_ws;
    __bf16* wbf = (__bf16*)((char*)d_ws + WBF_OFF);

    hipLaunchKernelGGL(setup_tiles, dim3(1), dim3(64), 0, stream, cnt, ws);
    hipLaunchKernelGGL(wcvt, dim3(2048), dim3(256), 0, stream, weight, wbf);
    hipLaunchKernelGGL(moe_gemm, dim3(TILES_TOTAL * 4), dim3(256), 0, stream,
                       inp, wbf, bias, ws, out);
}

// Round 9
// 221.374 us; speedup vs baseline: 1.1542x; 1.1542x over previous
//
#include <hip/hip_runtime.h>
#include <hip/hip_bf16.h>
#include <stdint.h>

#define NE    64
#define DIN   512
#define DOUT  512
#define TTOK  131072
#define BM    128
#define BN    128
#define BK    32
#define NK    (DIN / BK)              // 16 K-steps
#define TILES_TOTAL (TTOK / BM + NE)  // 1088
#define NXCD  8
#define TPX   (TILES_TOTAL / NXCD)    // 136

typedef __bf16 bf16x8_t __attribute__((ext_vector_type(8)));
typedef float  f32x4_t  __attribute__((ext_vector_type(4)));

// LDS (48 KB -> 3 blocks/CU; 512 thr/block -> 24 waves/CU = 6/SIMD):
//   A dbuf: 2 x 16384  (128 rows x 128B fp32; source-preswizzled (row&7))
//   B dbuf: 2 x 8192   (64 LDS rows x 128B bf16; row lr holds dout lr & lr+64)
#define ABUF(i) ((i) * 16384)
#define BBUF(i) (32768 + (i) * 8192)
#define LDS_BYTES 49152

#define WAITV0() asm volatile("s_waitcnt vmcnt(0)" ::: "memory")
#define SB() __builtin_amdgcn_sched_barrier(0)

// ws layout: ws[0] = ntiles; tile table (int4) at ws+4; bf16 weight at +32KB
#define WBF_OFF 32768

__global__ void setup_tiles(const int* __restrict__ cnt, int* __restrict__ ws) {
    int e = threadIdx.x;
    if (e >= NE) return;
    int off = 0, tbase = 0;
    for (int i = 0; i < e; ++i) {
        int c = cnt[i];
        off += c;
        tbase += (c + (BM - 1)) / BM;
    }
    int c = cnt[e];
    int nt = (c + (BM - 1)) / BM;
    int* tbl = ws + 4;
    for (int t = 0; t < nt; ++t) {
        int idx = tbase + t;
        tbl[4 * idx + 0] = e;
        tbl[4 * idx + 1] = off + t * BM;
        tbl[4 * idx + 2] = off + c;
        tbl[4 * idx + 3] = 0;
    }
    if (e == NE - 1) ws[0] = tbase + nt;
}

// weight fp32 -> bf16, streaming
__global__ __launch_bounds__(256) void wcvt(const float* __restrict__ w,
                                            __bf16* __restrict__ wbf) {
    const size_t stride = (size_t)gridDim.x * 256;
    size_t i = (size_t)blockIdx.x * 256 + threadIdx.x;
    const size_t n8 = (size_t)NE * DOUT * DIN / 8;
    for (; i < n8; i += stride) {
        f32x4_t a = *(const f32x4_t*)(w + i * 8);
        f32x4_t b = *(const f32x4_t*)(w + i * 8 + 4);
        bf16x8_t h;
#pragma unroll
        for (int j = 0; j < 4; ++j) {
            h[j]     = (__bf16)a[j];
            h[4 + j] = (__bf16)b[j];
        }
        *(bf16x8_t*)(wbf + i * 8) = h;
    }
}

__device__ __forceinline__ void gload16(const void* g, uint8_t* l) {
    __builtin_amdgcn_global_load_lds(
        (const __attribute__((address_space(1))) uint32_t*)g,
        (__attribute__((address_space(3))) uint32_t*)l, 16, 0, 0);
}

__global__ __launch_bounds__(512, 6) void moe_gemm(
    const float* __restrict__ inp,
    const __bf16* __restrict__ wbf,
    const float* __restrict__ bias,
    const int* __restrict__ ws,
    float* __restrict__ out)
{
    __shared__ __align__(16) uint8_t smem[LDS_BYTES];

    const int bid  = blockIdx.x;
    const int xcd  = bid & (NXCD - 1);
    const int slot = bid >> 3;
    const int tile = xcd * TPX + (slot >> 2);
    const int n0   = (slot & 3) * BN;

    const int ntiles = ws[0];
    if (tile >= ntiles) return;
    const int4 ti = ((const int4*)(ws + 4))[tile];
    const int e = ti.x, row0 = ti.y, row_end = ti.z;

    const int tid  = threadIdx.x;
    const int lane = tid & 63;
    const int wave = tid >> 6;         // 0..7
    const int dr = lane >> 3;          // row-in-8-group
    const int ac = lane & 7;           // dest 16B chunk (linear)
    const int u  = ac ^ dr;            // logical chunk (group base % 8 == 0)

    // ---- A staging: 2 gload16/thread, each 8 rows x 128B, source-preswizzled ----
    const float* asrc[2];
#pragma unroll
    for (int i = 0; i < 2; ++i) {
        int arow = wave * 16 + i * 8 + dr;
        int grow = row0 + arow;
        if (grow > row_end - 1) grow = row_end - 1;   // clamp (C-stores guarded)
        asrc[i] = inp + (size_t)grow * DIN + (u << 2);
    }
    auto issueA = [&](int t, int buf) {
        uint8_t* dst = smem + ABUF(buf) + wave * 2048;
#pragma unroll
        for (int i = 0; i < 2; ++i)
            gload16(asrc[i] + t * BK, dst + i * 1024);
    };

    // ---- B staging: 1 gload16/thread. LDS row lr (0..63), chunk-logical u:
    //   u<4 -> dout n0+lr (k-part u&3) ; u>=4 -> dout n0+lr+64 ----
    const int lr_st = wave * 8 + dr;
    const int dout  = n0 + lr_st + ((u >> 2) << 6);
    const __bf16* bsrc = wbf + (size_t)(e * DOUT + dout) * DIN + (u & 3) * 8;
    auto issueB = [&](int t, int buf) {
        gload16(bsrc + t * BK, smem + BBUF(buf) + wave * 1024);
    };

    // ---- compute: wave owns 32 rows x 64 cols (2 x 4 frags) ----
    const int wr = (wave >> 1) * 32;   // 4 M-bands of 32
    const int wc = (wave & 1) * 64;    // 2 N-bands of 64
    const int frow = lane & 15;
    const int kg   = lane >> 4;

    f32x4_t acc[2][4] = {};

    auto compute = [&](int buf) {
        bf16x8_t af[2], bg[4];
#pragma unroll
        for (int m = 0; m < 2; ++m) {
            const int row = wr + m * 16 + frow;
            const uint8_t* pa = smem + ABUF(buf) + row * 128;
            const int sw = (row & 7) << 4;
            f32x4_t q0 = *(const f32x4_t*)(pa + ((kg * 32)      ^ sw));
            f32x4_t q1 = *(const f32x4_t*)(pa + ((kg * 32 + 16) ^ sw));
#pragma unroll
            for (int j = 0; j < 4; ++j) {
                af[m][j]     = (__bf16)q0[j];
                af[m][4 + j] = (__bf16)q1[j];
            }
        }
#pragma unroll
        for (int n = 0; n < 4; ++n) {
            const int row = wc + n * 16 + frow;     // dout-row in tile (0..127)
            const int lr  = row & 63;
            const int h   = row >> 6;
            bg[n] = *(const bf16x8_t*)(smem + BBUF(buf) + lr * 128 +
                                       ((h * 64 + kg * 16) ^ ((lr & 7) << 4)));
        }
        __builtin_amdgcn_s_setprio(1);
#pragma unroll
        for (int m = 0; m < 2; ++m)
#pragma unroll
            for (int n = 0; n < 4; ++n)
                acc[m][n] = __builtin_amdgcn_mfma_f32_16x16x32_bf16(
                    af[m], bg[n], acc[m][n], 0, 0, 0);
        __builtin_amdgcn_s_setprio(0);
    };

    // ---- R7's proven 2-phase dbuf drain0 schedule (unchanged) ----
    issueA(0, 0);
    issueB(0, 0);
    WAITV0(); SB();
    __builtin_amdgcn_s_barrier();
#pragma unroll
    for (int t = 0; t < NK; ++t) {
        const int buf = t & 1;
        if (t + 1 < NK) {
            issueA(t + 1, buf ^ 1);
            issueB(t + 1, buf ^ 1);
        }
        compute(buf);
        if (t + 1 < NK) {
            WAITV0(); SB();
            __builtin_amdgcn_s_barrier();
        }
    }

    // ---- epilogue: C/D layout col = lane&15, row = (lane>>4)*4 + j [m89] ----
    const int crow = kg * 4;
    const int ccol = frow;
    float bv[4];
#pragma unroll
    for (int n = 0; n < 4; ++n)
        bv[n] = bias[e * DOUT + n0 + wc + n * 16 + ccol];
#pragma unroll
    for (int m = 0; m < 2; ++m) {
#pragma unroll
        for (int j = 0; j < 4; ++j) {
            const int grow = row0 + wr + m * 16 + crow + j;
            if (grow < row_end) {
                float* orow = out + (size_t)grow * DOUT + n0 + wc + ccol;
#pragma unroll
                for (int n = 0; n < 4; ++n)
                    orow[n * 16] = acc[m][n][j] + bv[n];
            }
        }
    }
}

extern "C" void kernel_launch(void* const* d_in, const int* in_sizes, int n_in,
                              void* d_out, int out_size, void* d_ws, size_t ws_size,
                              hipStream_t stream) {
    const float* inp    = (const float*)d_in[0];
    const float* weight = (const float*)d_in[1];
    const float* bias   = (const float*)d_in[2];
    const int* cnt      = (const int*)d_in[3];   // int64 in reference, delivered as int32
    float* out = (float*)d_out;
    int* ws = (int*)d_ws;
    __bf16* wbf = (__bf16*)((char*)d_ws + WBF_OFF);

    hipLaunchKernelGGL(setup_tiles, dim3(1), dim3(64), 0, stream, cnt, ws);
    hipLaunchKernelGGL(wcvt, dim3(2048), dim3(256), 0, stream, weight, wbf);
    hipLaunchKernelGGL(moe_gemm, dim3(TILES_TOTAL * 4), dim3(512), 0, stream,
                       inp, wbf, bias, ws, out);
}

// Round 10
// 199.967 us; speedup vs baseline: 1.2778x; 1.1071x over previous
//
#include <hip/hip_runtime.h>
#include <hip/hip_bf16.h>
#include <stdint.h>

#define NE    64
#define DIN   512
#define DOUT  512
#define TTOK  131072
#define BM    256
#define BN    256
#define BK    32
#define NK    (DIN / BK)              // 16 K-steps
#define TILES_TOTAL (TTOK / BM + NE)  // 576
#define NXCD  8
#define TPX   (TILES_TOTAL / NXCD)    // 72

typedef __bf16 bf16x8_t __attribute__((ext_vector_type(8)));
typedef float  f32x4_t  __attribute__((ext_vector_type(4)));

// LDS (96 KB -> 1 block/CU of 16 waves):
//   A dbuf: 2 x 32768  (256 rows x 128B fp32; source-preswizzled (row&7))
//   B dbuf: 2 x 16384  (128 LDS rows x 128B bf16; row lr holds dout lr & lr+128)
#define ABUF(i) ((i) * 32768)
#define BBUF(i) (65536 + (i) * 16384)
#define LDS_BYTES 98304

#define WAITV0() asm volatile("s_waitcnt vmcnt(0)" ::: "memory")
#define SB() __builtin_amdgcn_sched_barrier(0)

// ws layout: ws[0] = ntiles; tile table (int4) at ws+4; bf16 weight at +32KB
#define WBF_OFF 32768

__global__ void setup_tiles(const int* __restrict__ cnt, int* __restrict__ ws) {
    int e = threadIdx.x;
    if (e >= NE) return;
    int off = 0, tbase = 0;
    for (int i = 0; i < e; ++i) {
        int c = cnt[i];
        off += c;
        tbase += (c + (BM - 1)) / BM;
    }
    int c = cnt[e];
    int nt = (c + (BM - 1)) / BM;
    int* tbl = ws + 4;
    for (int t = 0; t < nt; ++t) {
        int idx = tbase + t;
        tbl[4 * idx + 0] = e;
        tbl[4 * idx + 1] = off + t * BM;
        tbl[4 * idx + 2] = off + c;
        tbl[4 * idx + 3] = 0;
    }
    if (e == NE - 1) ws[0] = tbase + nt;
}

// weight fp32 -> bf16, streaming
__global__ __launch_bounds__(256) void wcvt(const float* __restrict__ w,
                                            __bf16* __restrict__ wbf) {
    const size_t stride = (size_t)gridDim.x * 256;
    size_t i = (size_t)blockIdx.x * 256 + threadIdx.x;
    const size_t n8 = (size_t)NE * DOUT * DIN / 8;
    for (; i < n8; i += stride) {
        f32x4_t a = *(const f32x4_t*)(w + i * 8);
        f32x4_t b = *(const f32x4_t*)(w + i * 8 + 4);
        bf16x8_t h;
#pragma unroll
        for (int j = 0; j < 4; ++j) {
            h[j]     = (__bf16)a[j];
            h[4 + j] = (__bf16)b[j];
        }
        *(bf16x8_t*)(wbf + i * 8) = h;
    }
}

__device__ __forceinline__ void gload16(const void* g, uint8_t* l) {
    __builtin_amdgcn_global_load_lds(
        (const __attribute__((address_space(1))) uint32_t*)g,
        (__attribute__((address_space(3))) uint32_t*)l, 16, 0, 0);
}

__global__ __launch_bounds__(1024) void moe_gemm(
    const float* __restrict__ inp,
    const __bf16* __restrict__ wbf,
    const float* __restrict__ bias,
    const int* __restrict__ ws,
    float* __restrict__ out)
{
    __shared__ __align__(16) uint8_t smem[LDS_BYTES];

    const int bid  = blockIdx.x;
    const int xcd  = bid & (NXCD - 1);
    const int slot = bid >> 3;                 // 0..143
    const int tile = xcd * TPX + (slot >> 1);
    const int n0   = (slot & 1) * BN;

    const int ntiles = ws[0];
    if (tile >= ntiles) return;
    const int4 ti = ((const int4*)(ws + 4))[tile];
    const int e = ti.x, row0 = ti.y, row_end = ti.z;

    const int tid  = threadIdx.x;
    const int lane = tid & 63;
    const int wave = tid >> 6;         // 0..15
    const int dr = lane >> 3;          // row-in-8-group
    const int ac = lane & 7;           // dest 16B chunk (linear)
    const int u  = ac ^ dr;            // logical chunk (group base % 8 == 0)

    // ---- A staging: 2 gload16/wave, each 8 rows x 128B, source-preswizzled ----
    const float* asrc[2];
#pragma unroll
    for (int i = 0; i < 2; ++i) {
        int arow = wave * 16 + i * 8 + dr;
        int grow = row0 + arow;
        if (grow > row_end - 1) grow = row_end - 1;   // clamp (C-stores guarded)
        asrc[i] = inp + (size_t)grow * DIN + (u << 2);
    }
    auto issueA = [&](int t, int buf) {
        uint8_t* dst = smem + ABUF(buf) + wave * 2048;
#pragma unroll
        for (int i = 0; i < 2; ++i)
            gload16(asrc[i] + t * BK, dst + i * 1024);
    };

    // ---- B staging: 1 gload16/wave. LDS row lr (0..127), logical chunk u:
    //   u<4 -> dout n0+lr (k-part u&3) ; u>=4 -> dout n0+lr+128 ----
    const int lr_st = wave * 8 + dr;
    const int dout  = n0 + lr_st + ((u >> 2) << 7);
    const __bf16* bsrc = wbf + (size_t)(e * DOUT + dout) * DIN + (u & 3) * 8;
    auto issueB = [&](int t, int buf) {
        gload16(bsrc + t * BK, smem + BBUF(buf) + wave * 1024);
    };

    // ---- compute: wave owns 64 rows x 64 cols (4 x 4 frags) ----
    const int wr = (wave >> 2) * 64;   // 4 M-bands of 64
    const int wc = (wave & 3) * 64;    // 4 N-bands of 64
    const int frow = lane & 15;
    const int kg   = lane >> 4;

    f32x4_t acc[4][4] = {};

    auto compute = [&](int buf) {
        bf16x8_t af[4], bg[4];
#pragma unroll
        for (int m = 0; m < 4; ++m) {
            const int row = wr + m * 16 + frow;
            const uint8_t* pa = smem + ABUF(buf) + row * 128;
            const int sw = (row & 7) << 4;
            f32x4_t q0 = *(const f32x4_t*)(pa + ((kg * 32)      ^ sw));
            f32x4_t q1 = *(const f32x4_t*)(pa + ((kg * 32 + 16) ^ sw));
#pragma unroll
            for (int j = 0; j < 4; ++j) {
                af[m][j]     = (__bf16)q0[j];
                af[m][4 + j] = (__bf16)q1[j];
            }
        }
#pragma unroll
        for (int n = 0; n < 4; ++n) {
            const int row = wc + n * 16 + frow;     // dout-row in tile (0..255)
            const int lr  = row & 127;
            const int h   = row >> 7;
            bg[n] = *(const bf16x8_t*)(smem + BBUF(buf) + lr * 128 +
                                       ((h * 64 + kg * 16) ^ ((lr & 7) << 4)));
        }
        __builtin_amdgcn_s_setprio(1);
#pragma unroll
        for (int m = 0; m < 4; ++m)
#pragma unroll
            for (int n = 0; n < 4; ++n)
                acc[m][n] = __builtin_amdgcn_mfma_f32_16x16x32_bf16(
                    af[m], bg[n], acc[m][n], 0, 0, 0);
        __builtin_amdgcn_s_setprio(0);
    };

    // ---- proven 2-phase dbuf drain0 schedule ----
    issueA(0, 0);
    issueB(0, 0);
    WAITV0(); SB();
    __builtin_amdgcn_s_barrier();
#pragma unroll
    for (int t = 0; t < NK; ++t) {
        const int buf = t & 1;
        if (t + 1 < NK) {
            issueA(t + 1, buf ^ 1);
            issueB(t + 1, buf ^ 1);
        }
        compute(buf);
        if (t + 1 < NK) {
            WAITV0(); SB();
            __builtin_amdgcn_s_barrier();
        }
    }

    // ---- epilogue: C/D layout col = lane&15, row = (lane>>4)*4 + j [m89] ----
    const int crow = kg * 4;
    const int ccol = frow;
    float bv[4];
#pragma unroll
    for (int n = 0; n < 4; ++n)
        bv[n] = bias[e * DOUT + n0 + wc + n * 16 + ccol];
#pragma unroll
    for (int m = 0; m < 4; ++m) {
#pragma unroll
        for (int j = 0; j < 4; ++j) {
            const int grow = row0 + wr + m * 16 + crow + j;
            if (grow < row_end) {
                float* orow = out + (size_t)grow * DOUT + n0 + wc + ccol;
#pragma unroll
                for (int n = 0; n < 4; ++n)
                    orow[n * 16] = acc[m][n][j] + bv[n];
            }
        }
    }
}

extern "C" void kernel_launch(void* const* d_in, const int* in_sizes, int n_in,
                              void* d_out, int out_size, void* d_ws, size_t ws_size,
                              hipStream_t stream) {
    const float* inp    = (const float*)d_in[0];
    const float* weight = (const float*)d_in[1];
    const float* bias   = (const float*)d_in[2];
    const int* cnt      = (const int*)d_in[3];   // int64 in reference, delivered as int32
    float* out = (float*)d_out;
    int* ws = (int*)d_ws;
    __bf16* wbf = (__bf16*)((char*)d_ws + WBF_OFF);

    hipLaunchKernelGGL(setup_tiles, dim3(1), dim3(64), 0, stream, cnt, ws);
    hipLaunchKernelGGL(wcvt, dim3(2048), dim3(256), 0, stream, weight, wbf);
    hipLaunchKernelGGL(moe_gemm, dim3(TILES_TOTAL * 2), dim3(1024), 0, stream,
                       inp, wbf, bias, ws, out);
}